// Round 5
// baseline (67.975 us; speedup 1.0000x reference)
//
#include <hip/hip_runtime.h>

// Kendall tau: tau = sum_{i<j} tanh((p_i-p_j)(t_i-t_j)/T) / (n(n-1)/2), T=0.1.
// tanh(10d) = 1 - 2/(exp2(d*C)+1), C = 20/ln(2); exp2 saturation gives exact
// +-1 tails; the i==j self-pair gives rcp(2.0)=0.5 -> term exactly 0.
//
// Triangular tiling: 64 tiles x 128 elems -> 2080 tile-pairs (a<=b), processed
// TWO per block (grid 1040) with double-buffered LDS j-tiles and ONE barrier.
//  a<b : full 128x128 cross, each unordered pair once (weight 1)
//  a==b: full ordered cross incl self (self terms exactly 0), weight 1/2
// Per thread per phase: 1 i in regs, 64 j's from LDS (wave-uniform broadcast),
// 8 independent acc chains. Trans-pipe floor ~3.4 us for 33.5M pairs.

#define NTOT 8192
#define TILE 128
#define NT   (NTOT / TILE)            // 64
#define NPRS (NT * (NT + 1) / 2)      // 2080 tile-pairs
#define PPB  2                        // tile-pairs per block
#define NBLK (NPRS / PPB)             // 1040
#define TPB  256

__device__ __forceinline__ int rowoff(int a) {
    return a * NT - (a * (a - 1)) / 2;   // tile-pairs before row a of the triangle
}

__global__ __launch_bounds__(TPB) void ktau_tri(const float* __restrict__ pred,
                                                const float* __restrict__ targ,
                                                double* __restrict__ partial) {
    const float C = 28.853900817779268f;   // 2*10*log2(e)
    const int tid = threadIdx.x;
    const int il  = tid & (TILE - 1);      // i within tile
    const int jh  = tid >> 7;              // which 64-wide j half

    __shared__ float sjp[PPB][TILE];
    __shared__ float sjt[PPB][TILE];

    // Decode both tile-pairs and stage both j-tiles; A-tiles into regs. One barrier.
    int aa[PPB], bb[PPB];
    float pi[PPB], ti[PPB];
#pragma unroll
    for (int ph = 0; ph < PPB; ++ph) {
        const int pid = blockIdx.x * PPB + ph;
        int a = (int)((2.0 * NT + 1.0 -
                       sqrt((2.0 * NT + 1.0) * (2.0 * NT + 1.0) - 8.0 * (double)pid)) * 0.5);
        while (rowoff(a + 1) <= pid) ++a;
        while (a > 0 && rowoff(a) > pid) --a;
        const int b = a + (pid - rowoff(a));
        aa[ph] = a; bb[ph] = b;
        if (tid < TILE) {
            sjp[ph][tid] = pred[b * TILE + tid];
            sjt[ph][tid] = targ[b * TILE + tid] * C;
        }
        pi[ph] = pred[a * TILE + il];
        ti[ph] = targ[a * TILE + il] * C;
    }
    __syncthreads();

    double dacc = 0.0;
#pragma unroll
    for (int ph = 0; ph < PPB; ++ph) {
        float acc[8];
#pragma unroll
        for (int jj = 0; jj < 8; ++jj) acc[jj] = 0.0f;

        const float4* sp4 = (const float4*)sjp[ph];
        const float4* st4 = (const float4*)sjt[ph];
        const float api = pi[ph], ati = ti[ph];

#pragma unroll
        for (int jc = 0; jc < 8; ++jc) {       // 8 chunks of 8 j's in this thread's half
            const int q = jh * 16 + jc * 2;    // wave-uniform float4 index -> LDS broadcast
            const float4 pj0 = sp4[q], pj1 = sp4[q + 1];
            const float4 tj0 = st4[q], tj1 = st4[q + 1];
            const float pj[8] = {pj0.x, pj0.y, pj0.z, pj0.w, pj1.x, pj1.y, pj1.z, pj1.w};
            const float tj[8] = {tj0.x, tj0.y, tj0.z, tj0.w, tj1.x, tj1.y, tj1.z, tj1.w};
#pragma unroll
            for (int jj = 0; jj < 8; ++jj) {   // 8 independent chains
                const float x = (api - pj[jj]) * (ati - tj[jj]);
                const float e = __builtin_amdgcn_exp2f(x);        // inf/0 at tails
                const float r = __builtin_amdgcn_rcpf(e + 1.0f);  // rcp(inf)=0, rcp(2)=0.5
                acc[jj] = __builtin_fmaf(-2.0f, r, acc[jj]);      // term = 1 - 2r; +1 below
            }
        }

        float fsum = 0.0f;
#pragma unroll
        for (int jj = 0; jj < 8; ++jj) fsum += acc[jj];
        // +1 per each of this thread's 64 terms; diagonal tiles double-count -> x0.5 exact
        const double w = (aa[ph] == bb[ph]) ? 0.5 : 1.0;
        dacc += w * ((double)fsum + 64.0);
    }

    // block reduction in double
#pragma unroll
    for (int off = 32; off > 0; off >>= 1)
        dacc += __shfl_down(dacc, off, 64);
    __shared__ double red[TPB / 64];
    if ((tid & 63) == 0) red[tid >> 6] = dacc;
    __syncthreads();
    if (tid == 0) {
        double s = 0.0;
#pragma unroll
        for (int w2 = 0; w2 < TPB / 64; ++w2) s += red[w2];
        partial[blockIdx.x] = s;
    }
}

__global__ __launch_bounds__(256) void ktau_final(const double* __restrict__ partial,
                                                  float* __restrict__ out) {
    const int tid = threadIdx.x;
    double s = 0.0;
    for (int t = tid; t < NBLK; t += 256) s += partial[t];
#pragma unroll
    for (int off = 32; off > 0; off >>= 1)
        s += __shfl_down(s, off, 64);
    __shared__ double red[4];
    if ((tid & 63) == 0) red[tid >> 6] = s;
    __syncthreads();
    if (tid == 0) {
        const double n_pairs = (double)NTOT * (double)(NTOT - 1) * 0.5;  // 33550336
        out[0] = (float)((red[0] + red[1] + red[2] + red[3]) / n_pairs);
    }
}

extern "C" void kernel_launch(void* const* d_in, const int* in_sizes, int n_in,
                              void* d_out, int out_size, void* d_ws, size_t ws_size,
                              hipStream_t stream) {
    const float* pred = (const float*)d_in[0];
    const float* targ = (const float*)d_in[1];
    float* out = (float*)d_out;
    double* partial = (double*)d_ws;   // NBLK doubles = 8.3 KB

    ktau_tri<<<NBLK, TPB, 0, stream>>>(pred, targ, partial);
    ktau_final<<<1, 256, 0, stream>>>(partial, out);
}